// Round 4
// baseline (298.777 us; speedup 1.0000x reference)
//
#include <hip/hip_runtime.h>

namespace {

constexpr float FF[12] = {0.0144f, 0.0272f, 0.0526f, 0.0972f, 0.193f, 0.63f,
                          -0.63f, -0.193f, -0.0972f, -0.0526f, -0.0272f, -0.0144f};
constexpr float SQ2   = 1.41421356237309515f;
constexpr float NISQ2 = -0.70710678118654752f;

__device__ __forceinline__ void fma4(float4& o, float s, const float4& v) {
  o.x += s * v.x; o.y += s * v.y; o.z += s * v.z; o.w += s * v.w;
}

// hconv of one 20-float window -> one float4 (4 output cols). SH = 8 - O.
template <int SH>
__device__ __forceinline__ float4 hrow_conv(const float* w) {
  float4 o = make_float4(0.f, 0.f, 0.f, 0.f);
#pragma unroll
  for (int a = 0; a < 12; ++a) {
    const float fa = FF[a];
    o.x += fa * w[SH + 0 + a];
    o.y += fa * w[SH + 1 + a];
    o.z += fa * w[SH + 2 + a];
    o.w += fa * w[SH + 3 + a];
  }
  return o;
}

}  // namespace

// ---------------- Stage 1: fbrec(Y0, Y1, '2c', 'per') -> x (8,64,128,256) ----------------
// 512 threads, LDS 66 KB -> 2 blocks/CU (16 waves). One block per plane, 512 planes.
// VGPR cap 128 via launch_bounds(512,4); peak live ~94 by construction (no spill).
__global__ __launch_bounds__(512, 4) void s1_kernel(
    const float* __restrict__ y0, const float* __restrict__ y1,
    const float* __restrict__ y2, const float* __restrict__ y3,
    float* __restrict__ xout) {
  __shared__ float bufF[128 * 132];
  float4* buf4 = reinterpret_cast<float4*>(bufF);
  constexpr int SG = 33;  // row stride in float4 groups (32 + 1 pad)

  const int p  = blockIdx.x;
  const int b  = p >> 6;
  const int cc = p & 63;
  const int sub = (b * 32 + (cc & 31)) << 14;
  const float4* Y04 = reinterpret_cast<const float4*>((cc < 32 ? y1 : y2) + sub);
  const float4* Y14 = reinterpret_cast<const float4*>((cc < 32 ? y0 : y3) + sub);
  float4* xp4 = reinterpret_cast<float4*>(xout + (size_t)p * 32768);

  const int tid = threadIdx.x;
  const int j  = tid & 31;         // group 0..31
  const int i0 = (tid >> 5) * 8;   // strip base row

  // ---- P0: load Y0 plane -> S (coalesced, stride-1 LDS writes) ----
#pragma unroll
  for (int k = 0; k < 8; ++k) {
    const int idx = tid + k * 512;
    buf4[(idx >> 5) * SG + (idx & 31)] = Y04[idx];
  }
  __syncthreads();  // b0

  // ---- P1: grab x0 own tile; p1 = NISQ2*(Y1 + F5(Y0)); S := p1 ----
  float4 x0t[8];
#pragma unroll
  for (int k = 0; k < 8; ++k) x0t[k] = buf4[(i0 + k) * SG + j];

  float4 acc[8];
#pragma unroll
  for (int k = 0; k < 8; ++k) acc[k] = make_float4(0.f, 0.f, 0.f, 0.f);
#pragma unroll
  for (int d = 0; d < 19; ++d) {
    const int r = (i0 + d - 5) & 127;
    float w[20];
#pragma unroll
    for (int dg = 0; dg < 5; ++dg) {
      float4 v = buf4[r * SG + ((j + dg - 2) & 31)];
      w[4 * dg + 0] = v.x; w[4 * dg + 1] = v.y; w[4 * dg + 2] = v.z; w[4 * dg + 3] = v.w;
    }
    const float4 h = hrow_conv<3>(w);
#pragma unroll
    for (int k = 0; k < 8; ++k) {
      const int a = d - k;
      if (a >= 0 && a < 12) fma4(acc[k], FF[a], h);
    }
  }
#pragma unroll
  for (int k = 0; k < 8; ++k) {
    const float4 yv = Y14[(i0 + k) * 32 + j];
    acc[k].x = NISQ2 * (yv.x + acc[k].x);
    acc[k].y = NISQ2 * (yv.y + acc[k].y);
    acc[k].z = NISQ2 * (yv.z + acc[k].z);
    acc[k].w = NISQ2 * (yv.w + acc[k].w);
  }
  __syncthreads();  // b1: all Y0 reads from S done
#pragma unroll
  for (int k = 0; k < 8; ++k) buf4[(i0 + k) * SG + j] = acc[k];
  __syncthreads();  // b2: p1 visible

  // ---- P2: p0 = SQ2*x0 + F6(p1); THEN odd-gather (w dead); S := p0 ----
#pragma unroll
  for (int k = 0; k < 8; ++k) acc[k] = make_float4(0.f, 0.f, 0.f, 0.f);
#pragma unroll
  for (int d = 0; d < 19; ++d) {
    const int r = (i0 + d - 6) & 127;
    float w[20];
#pragma unroll
    for (int dg = 0; dg < 5; ++dg) {
      float4 v = buf4[r * SG + ((j + dg - 2) & 31)];
      w[4 * dg + 0] = v.x; w[4 * dg + 1] = v.y; w[4 * dg + 2] = v.z; w[4 * dg + 3] = v.w;
    }
    const float4 h = hrow_conv<2>(w);
#pragma unroll
    for (int k = 0; k < 8; ++k) {
      const int a = d - k;
      if (a >= 0 && a < 12) fma4(acc[k], FF[a], h);
    }
  }
#pragma unroll
  for (int k = 0; k < 8; ++k) {
    acc[k].x = SQ2 * x0t[k].x + acc[k].x;
    acc[k].y = SQ2 * x0t[k].y + acc[k].y;
    acc[k].z = SQ2 * x0t[k].z + acc[k].z;
    acc[k].w = SQ2 * x0t[k].w + acc[k].w;
  }
  // odd-J gather from S (= p1) into regs (x0t/w dead -> low pressure here)
  float xodd[32];
#pragma unroll
  for (int k = 0; k < 16; ++k) {
    const int t = tid + k * 512;
    const int i2 = t >> 6, j4o = t & 63;
    const int m0 = 1 - (i2 & 1);
#pragma unroll
    for (int h = 0; h < 2; ++h) {
      const int jo = 4 * j4o + m0 + 2 * h;
      const int J = (i2 + jo) & 255;
      const int c = J >> 1;
      const int r = (i2 - 1 - c) & 127;
      xodd[2 * k + h] = bufF[r * 132 + c];
    }
  }
  __syncthreads();  // b3: all p1 reads done
#pragma unroll
  for (int k = 0; k < 8; ++k) buf4[(i0 + k) * SG + j] = acc[k];
  __syncthreads();  // b4: p0 visible

  // ---- P3: even-J gather, merge odd regs, single coalesced write ----
#pragma unroll
  for (int k = 0; k < 16; ++k) {
    const int t = tid + k * 512;
    const int i2 = t >> 6, j4o = t & 63;
    float ev[2];
#pragma unroll
    for (int h = 0; h < 2; ++h) {
      const int me = (i2 & 1) + 2 * h;
      const int jo = 4 * j4o + me;
      const int J = (i2 + jo) & 255;
      const int c = J >> 1;
      const int r = (i2 - c) & 127;
      ev[h] = bufF[r * 132 + c];
    }
    const float o0 = xodd[2 * k + 0], o1 = xodd[2 * k + 1];
    const bool sw = (i2 & 1) != 0;
    xp4[t] = make_float4(sw ? o0 : ev[0], sw ? ev[0] : o0,
                         sw ? o1 : ev[1], sw ? ev[1] : o1);
  }
}

// ---------------- Stage 2: fbrec(x0, x1, '1r', 'qper_col') -> out (8,32,256,256) -----------
// 1024 threads, LDS 130 KB -> 1 block/CU (16 waves). One block per output plane, 256 planes.
__global__ __launch_bounds__(1024, 4) void s2_kernel(const float* __restrict__ x,
                                                     float* __restrict__ out) {
  __shared__ float bufF[128 * 260];
  float4* buf4 = reinterpret_cast<float4*>(bufF);
  constexpr int SG = 65;  // row stride in float4 groups (64 + 1 pad)

  const int q = blockIdx.x;
  const int b = q >> 5, c = q & 31;
  const float4* x04 = reinterpret_cast<const float4*>(x + (size_t)(b * 64 + c) * 32768);
  const float4* x14 = reinterpret_cast<const float4*>(x + (size_t)(b * 64 + 32 + c) * 32768);
  float4* op4 = reinterpret_cast<float4*>(out + (size_t)q * 65536);

  const int tid = threadIdx.x;
  const int j  = tid & 63;
  const int i0 = (tid >> 6) * 8;

  // ---- P0: load x0 -> S ----
#pragma unroll
  for (int k = 0; k < 8; ++k) {
    const int idx = tid + k * 1024;
    buf4[(idx >> 6) * SG + (idx & 63)] = x04[idx];
  }
  __syncthreads();  // b0

  // ---- P1: grab x0 own tile; p1 = NISQ2*(x1 + F5(x0^qper)); S := p1 ----
  float4 x0t[8];
#pragma unroll
  for (int k = 0; k < 8; ++k) x0t[k] = buf4[(i0 + k) * SG + j];

  float4 acc[8];
#pragma unroll
  for (int k = 0; k < 8; ++k) acc[k] = make_float4(0.f, 0.f, 0.f, 0.f);
#pragma unroll
  for (int d = 0; d < 19; ++d) {
    const int rr = i0 + d - 5;
    const int r = rr & 127;
    const int gx = ((unsigned)rr < 128u) ? 0 : 32;  // qper_col wrap -> col+128
    float w[20];
#pragma unroll
    for (int dg = 0; dg < 5; ++dg) {
      float4 v = buf4[r * SG + (((j + dg - 2) & 63) ^ gx)];
      w[4 * dg + 0] = v.x; w[4 * dg + 1] = v.y; w[4 * dg + 2] = v.z; w[4 * dg + 3] = v.w;
    }
    const float4 h = hrow_conv<3>(w);
#pragma unroll
    for (int k = 0; k < 8; ++k) {
      const int a = d - k;
      if (a >= 0 && a < 12) fma4(acc[k], FF[a], h);
    }
  }
#pragma unroll
  for (int k = 0; k < 8; ++k) {
    const float4 xv = x14[(i0 + k) * 64 + j];
    acc[k].x = NISQ2 * (xv.x + acc[k].x);
    acc[k].y = NISQ2 * (xv.y + acc[k].y);
    acc[k].z = NISQ2 * (xv.z + acc[k].z);
    acc[k].w = NISQ2 * (xv.w + acc[k].w);
  }
  __syncthreads();  // b1
#pragma unroll
  for (int k = 0; k < 8; ++k) buf4[(i0 + k) * SG + j] = acc[k];
  __syncthreads();  // b2: p1 visible

  // ---- P2: p0 = SQ2*x0 + F6(p1^qper); THEN odd-gather; S := p0 ----
#pragma unroll
  for (int k = 0; k < 8; ++k) acc[k] = make_float4(0.f, 0.f, 0.f, 0.f);
#pragma unroll
  for (int d = 0; d < 19; ++d) {
    const int rr = i0 + d - 6;
    const int r = rr & 127;
    const int gx = ((unsigned)rr < 128u) ? 0 : 32;
    float w[20];
#pragma unroll
    for (int dg = 0; dg < 5; ++dg) {
      float4 v = buf4[r * SG + (((j + dg - 2) & 63) ^ gx)];
      w[4 * dg + 0] = v.x; w[4 * dg + 1] = v.y; w[4 * dg + 2] = v.z; w[4 * dg + 3] = v.w;
    }
    const float4 h = hrow_conv<2>(w);
#pragma unroll
    for (int k = 0; k < 8; ++k) {
      const int a = d - k;
      if (a >= 0 && a < 12) fma4(acc[k], FF[a], h);
    }
  }
#pragma unroll
  for (int k = 0; k < 8; ++k) {
    acc[k].x = SQ2 * x0t[k].x + acc[k].x;
    acc[k].y = SQ2 * x0t[k].y + acc[k].y;
    acc[k].z = SQ2 * x0t[k].z + acc[k].z;
    acc[k].w = SQ2 * x0t[k].w + acc[k].w;
  }
  float oodd[32];
#pragma unroll
  for (int k = 0; k < 16; ++k) {
    const int t = tid + k * 1024;
    const int i2 = t >> 6, j4o = t & 63;
    const int m0 = 1 - (i2 & 1);
#pragma unroll
    for (int h = 0; h < 2; ++h) {
      const int jo = 4 * j4o + m0 + 2 * h;
      const int I = (i2 + jo) & 255;
      const int r2 = I >> 1;
      const int c2 = (jo - 1 - r2) & 255;
      oodd[2 * k + h] = bufF[r2 * 260 + c2];
    }
  }
  __syncthreads();  // b3
#pragma unroll
  for (int k = 0; k < 8; ++k) buf4[(i0 + k) * SG + j] = acc[k];
  __syncthreads();  // b4: p0 visible

  // ---- P3: even-I gather, merge odd regs, coalesced write ----
#pragma unroll
  for (int k = 0; k < 16; ++k) {
    const int t = tid + k * 1024;
    const int i2 = t >> 6, j4o = t & 63;
    float ev[2];
#pragma unroll
    for (int h = 0; h < 2; ++h) {
      const int me = (i2 & 1) + 2 * h;
      const int jo = 4 * j4o + me;
      const int I = (i2 + jo) & 255;
      const int r2 = I >> 1;
      const int c2 = (jo - r2) & 255;
      ev[h] = bufF[r2 * 260 + c2];
    }
    const float o0 = oodd[2 * k + 0], o1 = oodd[2 * k + 1];
    const bool sw = (i2 & 1) != 0;
    op4[t] = make_float4(sw ? o0 : ev[0], sw ? ev[0] : o0,
                         sw ? o1 : ev[1], sw ? ev[1] : o1);
  }
}

extern "C" void kernel_launch(void* const* d_in, const int* in_sizes, int n_in,
                              void* d_out, int out_size, void* d_ws, size_t ws_size,
                              hipStream_t stream) {
  const float* y0 = (const float*)d_in[0];
  const float* y1 = (const float*)d_in[1];
  const float* y2 = (const float*)d_in[2];
  const float* y3 = (const float*)d_in[3];
  float* xws = (float*)d_ws;           // (8,64,128,256) fp32 = 64 MiB intermediate
  float* outp = (float*)d_out;         // (8,32,256,256) fp32

  s1_kernel<<<512, 512, 0, stream>>>(y0, y1, y2, y3, xws);
  s2_kernel<<<256, 1024, 0, stream>>>(xws, outp);
}

// Round 5
// 260.564 us; speedup vs baseline: 1.1467x; 1.1467x over previous
//
#include <hip/hip_runtime.h>

namespace {

constexpr float FF[12] = {0.0144f, 0.0272f, 0.0526f, 0.0972f, 0.193f, 0.63f,
                          -0.63f, -0.193f, -0.0972f, -0.0526f, -0.0272f, -0.0144f};
constexpr float SQ2   = 1.41421356237309515f;
constexpr float NISQ2 = -0.70710678118654752f;

__device__ __forceinline__ void fma4(float4& o, float s, const float4& v) {
  o.x += s * v.x; o.y += s * v.y; o.z += s * v.z; o.w += s * v.w;
}

// hconv of one 20-float window -> one float4 (4 output cols). SH = 8 - O.
template <int SH>
__device__ __forceinline__ float4 hrow_conv(const float* w) {
  float4 o = make_float4(0.f, 0.f, 0.f, 0.f);
#pragma unroll
  for (int a = 0; a < 12; ++a) {
    const float fa = FF[a];
    o.x += fa * w[SH + 0 + a];
    o.y += fa * w[SH + 1 + a];
    o.z += fa * w[SH + 2 + a];
    o.w += fa * w[SH + 3 + a];
  }
  return o;
}

// Fused separable conv (s1: plain periodic rows, 32 groups/row, no pad).
// acc[k] = F_O(S)[i0+k, 4j..4j+3],  O in {5,6}.
template <int O>
__device__ __forceinline__ void conv_s1(const float4* S, int i0, int j, float4 acc[8]) {
#pragma unroll
  for (int k = 0; k < 8; ++k) acc[k] = make_float4(0.f, 0.f, 0.f, 0.f);
#pragma unroll
  for (int d = 0; d < 19; ++d) {
    const int r = (i0 + d - O) & 127;
    float w[20];
#pragma unroll
    for (int dg = 0; dg < 5; ++dg) {
      float4 v = S[r * 32 + ((j + dg - 2) & 31)];
      w[4 * dg + 0] = v.x; w[4 * dg + 1] = v.y; w[4 * dg + 2] = v.z; w[4 * dg + 3] = v.w;
    }
    const float4 h = hrow_conv<8 - O>(w);
#pragma unroll
    for (int k = 0; k < 8; ++k) {
      const int a = d - k;
      if (a >= 0 && a < 12) fma4(acc[k], FF[a], h);
    }
  }
}

// Fused separable conv (s2: qper_col rows -> wrapped row reads col+128 == group^32).
template <int O>
__device__ __forceinline__ void conv_s2(const float4* S, int i0, int j, float4 acc[8]) {
#pragma unroll
  for (int k = 0; k < 8; ++k) acc[k] = make_float4(0.f, 0.f, 0.f, 0.f);
#pragma unroll
  for (int d = 0; d < 19; ++d) {
    const int rr = i0 + d - O;
    const int r = rr & 127;
    const int gx = ((unsigned)rr < 128u) ? 0 : 32;
    float w[20];
#pragma unroll
    for (int dg = 0; dg < 5; ++dg) {
      float4 v = S[r * 64 + (((j + dg - 2) & 63) ^ gx)];
      w[4 * dg + 0] = v.x; w[4 * dg + 1] = v.y; w[4 * dg + 2] = v.z; w[4 * dg + 3] = v.w;
    }
    const float4 h = hrow_conv<8 - O>(w);
#pragma unroll
    for (int k = 0; k < 8; ++k) {
      const int a = d - k;
      if (a >= 0 && a < 12) fma4(acc[k], FF[a], h);
    }
  }
}

}  // namespace

// ---------------- Stage 1: fbrec(Y0, Y1, '2c', 'per') -> x (8,64,128,256) ----------------
// 512 threads, LDS 64 KB (no pad) -> 2 blocks/CU, one round of 512 blocks.
__global__ __launch_bounds__(512, 4) void s1_kernel(
    const float* __restrict__ y0, const float* __restrict__ y1,
    const float* __restrict__ y2, const float* __restrict__ y3,
    float* __restrict__ xout) {
  __shared__ float S[128 * 128];
  float4* S4 = reinterpret_cast<float4*>(S);

  const int p  = blockIdx.x;
  const int b  = p >> 6;
  const int cc = p & 63;
  const int sub = (b * 32 + (cc & 31)) << 14;
  const float4* Y04 = reinterpret_cast<const float4*>((cc < 32 ? y1 : y2) + sub);
  const float4* Y14 = reinterpret_cast<const float4*>((cc < 32 ? y0 : y3) + sub);
  float* xp = xout + (size_t)p * 32768;

  const int tid = threadIdx.x;
  const int j  = tid & 31;
  const int i0 = (tid >> 5) * 8;

  // P0: load Y0 -> S (linear)
#pragma unroll
  for (int k = 0; k < 8; ++k) {
    const int idx = tid + k * 512;
    S4[idx] = Y04[idx];
  }
  __syncthreads();

  // P1: p1 = NISQ2*(Y1 + F5(Y0));  S := p1
  float4 acc[8];
  conv_s1<5>(S4, i0, j, acc);
#pragma unroll
  for (int k = 0; k < 8; ++k) {
    const float4 yv = Y14[(i0 + k) * 32 + j];
    acc[k].x = NISQ2 * (yv.x + acc[k].x);
    acc[k].y = NISQ2 * (yv.y + acc[k].y);
    acc[k].z = NISQ2 * (yv.z + acc[k].z);
    acc[k].w = NISQ2 * (yv.w + acc[k].w);
  }
  __syncthreads();
#pragma unroll
  for (int k = 0; k < 8; ++k) S4[(i0 + k) * 32 + j] = acc[k];
  __syncthreads();  // p1 visible

  // P2a: odd-J outputs straight to global (scalar, stride-2).
  // x[i,jo], J=(i+jo)&255 odd: val = p1[(i-1-J/2)&127, J/2]
#pragma unroll
  for (int k = 0; k < 32; ++k) {
    const int t = tid + k * 512;          // 16384 odd positions
    const int i = t >> 7;
    const int u = t & 127;
    const int jo = 2 * u + ((i + 1) & 1);
    const int J = (i + jo) & 255;
    const int c = J >> 1;
    const int r = (i - 1 - c) & 127;
    xp[i * 256 + jo] = S[r * 128 + c];
  }

  // P2b: p0 = SQ2*Y0 + F6(p1);  S := p0   (Y0 re-read from global/L2)
  conv_s1<6>(S4, i0, j, acc);
#pragma unroll
  for (int k = 0; k < 8; ++k) {
    const float4 yv = Y04[(i0 + k) * 32 + j];
    acc[k].x = SQ2 * yv.x + acc[k].x;
    acc[k].y = SQ2 * yv.y + acc[k].y;
    acc[k].z = SQ2 * yv.z + acc[k].z;
    acc[k].w = SQ2 * yv.w + acc[k].w;
  }
  __syncthreads();  // all p1 reads (conv + gathers) done
#pragma unroll
  for (int k = 0; k < 8; ++k) S4[(i0 + k) * 32 + j] = acc[k];
  __syncthreads();  // p0 visible

  // P3: even-J outputs. val = p0[(i-J/2)&127, J/2]
#pragma unroll
  for (int k = 0; k < 32; ++k) {
    const int t = tid + k * 512;
    const int i = t >> 7;
    const int u = t & 127;
    const int jo = 2 * u + (i & 1);
    const int J = (i + jo) & 255;
    const int c = J >> 1;
    const int r = (i - c) & 127;
    xp[i * 256 + jo] = S[r * 128 + c];
  }
}

// ---------------- Stage 2: fbrec(x0, x1, '1r', 'qper_col') -> out (8,32,256,256) -----------
// 1024 threads, LDS 128 KB (no pad) -> 1 block/CU, one round of 256 blocks.
__global__ __launch_bounds__(1024, 4) void s2_kernel(const float* __restrict__ x,
                                                     float* __restrict__ out) {
  __shared__ float S[128 * 256];
  float4* S4 = reinterpret_cast<float4*>(S);

  const int q = blockIdx.x;
  const int b = q >> 5, c = q & 31;
  const float4* x04 = reinterpret_cast<const float4*>(x + (size_t)(b * 64 + c) * 32768);
  const float4* x14 = reinterpret_cast<const float4*>(x + (size_t)(b * 64 + 32 + c) * 32768);
  float* op = out + (size_t)q * 65536;

  const int tid = threadIdx.x;
  const int j  = tid & 63;
  const int i0 = (tid >> 6) * 8;

  // P0: load x0 -> S (linear)
#pragma unroll
  for (int k = 0; k < 8; ++k) {
    const int idx = tid + k * 1024;
    S4[idx] = x04[idx];
  }
  __syncthreads();

  // P1: p1 = NISQ2*(x1 + F5(x0^qper));  S := p1
  float4 acc[8];
  conv_s2<5>(S4, i0, j, acc);
#pragma unroll
  for (int k = 0; k < 8; ++k) {
    const float4 xv = x14[(i0 + k) * 64 + j];
    acc[k].x = NISQ2 * (xv.x + acc[k].x);
    acc[k].y = NISQ2 * (xv.y + acc[k].y);
    acc[k].z = NISQ2 * (xv.z + acc[k].z);
    acc[k].w = NISQ2 * (xv.w + acc[k].w);
  }
  __syncthreads();
#pragma unroll
  for (int k = 0; k < 8; ++k) S4[(i0 + k) * 64 + j] = acc[k];
  __syncthreads();  // p1 visible

  // P2a: odd-I outputs straight to global.
  // out[i,jo], I=(i+jo)&255 odd, r=I>>1: val = p1[r, (jo-1-r)&255]
#pragma unroll
  for (int k = 0; k < 32; ++k) {
    const int t = tid + k * 1024;         // 32768 odd positions
    const int i = t >> 7;
    const int u = t & 127;
    const int jo = 2 * u + ((i + 1) & 1);
    const int I = (i + jo) & 255;
    const int r2 = I >> 1;
    const int c2 = (jo - 1 - r2) & 255;
    op[i * 256 + jo] = S[r2 * 256 + c2];
  }

  // P2b: p0 = SQ2*x0 + F6(p1^qper);  S := p0   (x0 re-read from global/L2)
  conv_s2<6>(S4, i0, j, acc);
#pragma unroll
  for (int k = 0; k < 8; ++k) {
    const float4 xv = x04[(i0 + k) * 64 + j];
    acc[k].x = SQ2 * xv.x + acc[k].x;
    acc[k].y = SQ2 * xv.y + acc[k].y;
    acc[k].z = SQ2 * xv.z + acc[k].z;
    acc[k].w = SQ2 * xv.w + acc[k].w;
  }
  __syncthreads();  // all p1 reads done
#pragma unroll
  for (int k = 0; k < 8; ++k) S4[(i0 + k) * 64 + j] = acc[k];
  __syncthreads();  // p0 visible

  // P3: even-I outputs. val = p0[r, (jo-r)&255]
#pragma unroll
  for (int k = 0; k < 32; ++k) {
    const int t = tid + k * 1024;
    const int i = t >> 7;
    const int u = t & 127;
    const int jo = 2 * u + (i & 1);
    const int I = (i + jo) & 255;
    const int r2 = I >> 1;
    const int c2 = (jo - r2) & 255;
    op[i * 256 + jo] = S[r2 * 256 + c2];
  }
}

extern "C" void kernel_launch(void* const* d_in, const int* in_sizes, int n_in,
                              void* d_out, int out_size, void* d_ws, size_t ws_size,
                              hipStream_t stream) {
  const float* y0 = (const float*)d_in[0];
  const float* y1 = (const float*)d_in[1];
  const float* y2 = (const float*)d_in[2];
  const float* y3 = (const float*)d_in[3];
  float* xws = (float*)d_ws;           // (8,64,128,256) fp32 = 64 MiB intermediate
  float* outp = (float*)d_out;         // (8,32,256,256) fp32

  s1_kernel<<<512, 512, 0, stream>>>(y0, y1, y2, y3, xws);
  s2_kernel<<<256, 1024, 0, stream>>>(xws, outp);
}